// Round 1
// baseline (561.764 us; speedup 1.0000x reference)
//
#include <hip/hip_runtime.h>
#include <hip/hip_bf16.h>
#include <stdint.h>

// Problem dims (fixed)
#define BB 4
#define LQ 2048
#define LK 2048
#define DD 1024
#define HH 16
#define HD 64
#define MM (BB * LQ)  // 8192

typedef __attribute__((ext_vector_type(8))) short short8;
typedef __attribute__((ext_vector_type(4))) float f32x4;

__device__ __forceinline__ unsigned short f2bf(float x) {
  uint32_t u = __float_as_uint(x);
  u += 0x7fffu + ((u >> 16) & 1u);  // round-to-nearest-even
  return (unsigned short)(u >> 16);
}

#define GLD16(g, l)                                                  \
  __builtin_amdgcn_global_load_lds(                                  \
      (const __attribute__((address_space(1))) void*)(g),            \
      (__attribute__((address_space(3))) void*)(l), 16, 0, 0)

// ---------------- fp32 -> bf16 cast (vectorized) ----------------
__global__ __launch_bounds__(256) void cast_bf16(const float* __restrict__ in,
                                                 unsigned short* __restrict__ out,
                                                 int n4) {
  int i = blockIdx.x * 256 + threadIdx.x;
  if (i >= n4) return;
  float4 v = ((const float4*)in)[i];
  ushort4 o;
  o.x = f2bf(v.x); o.y = f2bf(v.y); o.z = f2bf(v.z); o.w = f2bf(v.w);
  ((ushort4*)out)[i] = o;
}

// ---------------- QKV projection GEMM (m97-style 128x128 tile) ----------------
// out[m,n] = sum_k A[m,k]*W[n,k] + bias[n]   (A:[8192,1024] bf16, W:[1024,1024] bf16)
// z=0: A=hs  -> Q  layout [B,H,LQ,HD]
// z=1: A=ctx -> K  layout [B,H,LK,HD]
// z=2: A=ctx -> Vt layout [B,H,HD,LK]  (transposed for PV B-operand)
__global__ __launch_bounds__(256) void gemm_proj(
    const unsigned short* __restrict__ hs, const unsigned short* __restrict__ ctx,
    const unsigned short* __restrict__ qw, const unsigned short* __restrict__ kw,
    const unsigned short* __restrict__ vw,
    const float* __restrict__ qb, const float* __restrict__ kb,
    const float* __restrict__ vb,
    unsigned short* __restrict__ Qo, unsigned short* __restrict__ Ko,
    unsigned short* __restrict__ Vt) {
  __shared__ unsigned short sA[128 * 32];
  __shared__ unsigned short sB[128 * 32];

  const int z = blockIdx.z;
  const unsigned short* A = (z == 0) ? hs : ctx;
  const unsigned short* W = (z == 0) ? qw : (z == 1 ? kw : vw);
  const float* bias = (z == 0) ? qb : (z == 1 ? kb : vb);
  unsigned short* out = (z == 0) ? Qo : (z == 1 ? Ko : Vt);

  const int m0 = blockIdx.x * 128;
  const int n0 = blockIdx.y * 128;
  const int t = threadIdx.x;
  const int lane = t & 63;
  const int w = t >> 6;
  const int wrow = w >> 1, wcol = w & 1;
  const int l15 = lane & 15, lg = lane >> 4;

  f32x4 acc[4][4];
#pragma unroll
  for (int i = 0; i < 4; i++)
#pragma unroll
    for (int j = 0; j < 4; j++) acc[i][j] = (f32x4){0.f, 0.f, 0.f, 0.f};

  const int c0 = t, c1 = t + 256;
  const int r0 = c0 >> 2, cc0 = (c0 & 3) * 8;
  const int r1 = c1 >> 2, cc1 = (c1 & 3) * 8;

  for (int k0 = 0; k0 < 1024; k0 += 32) {
    GLD16(A + (size_t)(m0 + r0) * 1024 + k0 + cc0, sA + (c0 & ~63) * 8);
    GLD16(W + (size_t)(n0 + r0) * 1024 + k0 + cc0, sB + (c0 & ~63) * 8);
    GLD16(A + (size_t)(m0 + r1) * 1024 + k0 + cc1, sA + (c1 & ~63) * 8);
    GLD16(W + (size_t)(n0 + r1) * 1024 + k0 + cc1, sB + (c1 & ~63) * 8);
    __syncthreads();

    short8 af[4], bf[4];
#pragma unroll
    for (int i = 0; i < 4; i++) {
      af[i] = *(const short8*)(sA + (wrow * 64 + i * 16 + l15) * 32 + lg * 8);
      bf[i] = *(const short8*)(sB + (wcol * 64 + i * 16 + l15) * 32 + lg * 8);
    }
#pragma unroll
    for (int i = 0; i < 4; i++)
#pragma unroll
      for (int j = 0; j < 4; j++)
        acc[i][j] = __builtin_amdgcn_mfma_f32_16x16x32_bf16(af[i], bf[j], acc[i][j], 0, 0, 0);
    __syncthreads();
  }

#pragma unroll
  for (int i = 0; i < 4; i++) {
    const int rowb = m0 + wrow * 64 + i * 16 + lg * 4;
#pragma unroll
    for (int j = 0; j < 4; j++) {
      const int col = n0 + wcol * 64 + j * 16 + l15;
      const float bv = bias[col];
      const int hh = col >> 6, hd = col & 63;
#pragma unroll
      for (int r = 0; r < 4; r++) {
        const int m = rowb + r;
        const int bidx = m >> 11, l = m & 2047;
        const float v = acc[i][j][r] + bv;
        size_t o;
        if (z < 2)
          o = (((size_t)(bidx * HH + hh) * 2048 + l) * HD + hd);
        else
          o = (((size_t)(bidx * HH + hh) * HD + hd) * 2048 + l);
        out[o] = f2bf(v);
      }
    }
  }
}

// ---------------- flash attention ----------------
// grid: (LQ/64, H, B), 256 threads = 4 waves, wave handles 16 q-rows.
__global__ __launch_bounds__(256) void attn_kernel(
    const unsigned short* __restrict__ Q, const unsigned short* __restrict__ K,
    const unsigned short* __restrict__ Vt, const int* __restrict__ amask,
    float* __restrict__ out) {
  __shared__ unsigned short pbuf[4][16 * 40];  // per-wave P repack, padded stride 40

  const int b = blockIdx.z, h = blockIdx.y;
  const int t = threadIdx.x, lane = t & 63, w = t >> 6;
  const int q0 = blockIdx.x * 64 + w * 16;
  const int bh = b * HH + h;
  const int l15 = lane & 15, lg = lane >> 4;

  const unsigned short* Qp = Q + ((size_t)bh * LQ + q0) * HD;
  const unsigned short* Kp = K + (size_t)bh * LK * HD;
  const unsigned short* Vp = Vt + (size_t)bh * HD * LK;
  const int* mrow = amask + b * LK;

  const short8 qf0 = *(const short8*)(Qp + l15 * HD + lg * 8);
  const short8 qf1 = *(const short8*)(Qp + l15 * HD + 32 + lg * 8);

  f32x4 acc[4];
#pragma unroll
  for (int d = 0; d < 4; d++) acc[d] = (f32x4){0.f, 0.f, 0.f, 0.f};
  float mrun[4] = {-1e30f, -1e30f, -1e30f, -1e30f};
  float se[4] = {0.f, 0.f, 0.f, 0.f};

  unsigned short* pb = pbuf[w];
  const f32x4 z4 = (f32x4){0.f, 0.f, 0.f, 0.f};

  for (int k0 = 0; k0 < LK; k0 += 32) {
    // --- scores: S[16q x 32k] as two 16x16 C-frags ---
    f32x4 st[2];
#pragma unroll
    for (int tt = 0; tt < 2; tt++) {
      const unsigned short* Kr = Kp + (size_t)(k0 + tt * 16 + l15) * HD + lg * 8;
      short8 kf0 = *(const short8*)(Kr);
      short8 kf1 = *(const short8*)(Kr + 32);
      st[tt] = __builtin_amdgcn_mfma_f32_16x16x32_bf16(qf0, kf0, z4, 0, 0, 0);
      st[tt] = __builtin_amdgcn_mfma_f32_16x16x32_bf16(qf1, kf1, st[tt], 0, 0, 0);
    }

    // scale + mask (masked -> -1e30, finite so no NaN paths)
    float p[2][4];
#pragma unroll
    for (int tt = 0; tt < 2; tt++) {
      const float madd = (mrow[k0 + tt * 16 + l15] > 0) ? -1e30f : 0.f;
#pragma unroll
      for (int r = 0; r < 4; r++) p[tt][r] = st[tt][r] * 0.125f + madd;
    }

    // row max across 32 k (cols live on lanes l15 within 16-lane groups)
    float lm[4];
#pragma unroll
    for (int r = 0; r < 4; r++) lm[r] = fmaxf(p[0][r], p[1][r]);
#pragma unroll
    for (int md = 1; md <= 8; md <<= 1)
#pragma unroll
      for (int r = 0; r < 4; r++) lm[r] = fmaxf(lm[r], __shfl_xor(lm[r], md));

    float fac[4];
#pragma unroll
    for (int r = 0; r < 4; r++) {
      const float nm = fmaxf(mrun[r], lm[r]);
      fac[r] = __expf(mrun[r] - nm);
      mrun[r] = nm;
    }

    // p = exp(s - m), row sum
    float ls[4];
#pragma unroll
    for (int r = 0; r < 4; r++) {
      p[0][r] = __expf(p[0][r] - mrun[r]);
      p[1][r] = __expf(p[1][r] - mrun[r]);
      ls[r] = p[0][r] + p[1][r];
    }
#pragma unroll
    for (int md = 1; md <= 8; md <<= 1)
#pragma unroll
      for (int r = 0; r < 4; r++) ls[r] += __shfl_xor(ls[r], md);
#pragma unroll
    for (int r = 0; r < 4; r++) se[r] = se[r] * fac[r] + ls[r];

    // rescale O accumulator
#pragma unroll
    for (int d = 0; d < 4; d++)
#pragma unroll
      for (int r = 0; r < 4; r++) acc[d][r] *= fac[r];

    // --- repack P (C-frag) -> A-frag via per-wave LDS ---
#pragma unroll
    for (int tt = 0; tt < 2; tt++)
#pragma unroll
      for (int r = 0; r < 4; r++)
        pb[(lg * 4 + r) * 40 + tt * 16 + l15] = f2bf(p[tt][r]);
    __syncthreads();
    const short8 pf = *(const short8*)(pb + l15 * 40 + lg * 8);

    // --- PV: ctx += P[16x32] * V[32 x 64] (Vt gives contiguous B-frags) ---
#pragma unroll
    for (int d = 0; d < 4; d++) {
      short8 vf = *(const short8*)(Vp + (size_t)(d * 16 + l15) * LK + k0 + lg * 8);
      acc[d] = __builtin_amdgcn_mfma_f32_16x16x32_bf16(pf, vf, acc[d], 0, 0, 0);
    }
  }

  // epilogue: out[b, q, h*64 + d] fp32
#pragma unroll
  for (int r = 0; r < 4; r++) {
    const float inv = 1.f / se[r];
    const int q = q0 + lg * 4 + r;
    float* orow = out + ((size_t)b * LQ + q) * DD + h * HD;
#pragma unroll
    for (int d = 0; d < 4; d++) orow[d * 16 + l15] = acc[d][r] * inv;
  }
}

extern "C" void kernel_launch(void* const* d_in, const int* in_sizes, int n_in,
                              void* d_out, int out_size, void* d_ws, size_t ws_size,
                              hipStream_t stream) {
  const float* hs = (const float*)d_in[0];
  const float* ctx = (const float*)d_in[1];
  const int* amask = (const int*)d_in[2];
  const float* q_w = (const float*)d_in[3];
  const float* q_b = (const float*)d_in[4];
  const float* k_w = (const float*)d_in[5];
  const float* k_b = (const float*)d_in[6];
  const float* v_w = (const float*)d_in[7];
  const float* v_b = (const float*)d_in[8];
  float* out = (float*)d_out;

  // workspace carve-up (ushort elements)
  unsigned short* ws = (unsigned short*)d_ws;
  unsigned short* hs_bf = ws;                     // 8192*1024
  unsigned short* ctx_bf = hs_bf + 8388608;       // 8192*1024
  unsigned short* qw_bf = ctx_bf + 8388608;       // 1024*1024
  unsigned short* kw_bf = qw_bf + 1048576;
  unsigned short* vw_bf = kw_bf + 1048576;
  unsigned short* Qb = vw_bf + 1048576;           // [B,H,LQ,HD]
  unsigned short* Kb = Qb + 8388608;              // [B,H,LK,HD]
  unsigned short* Vtb = Kb + 8388608;             // [B,H,HD,LK]

  // casts
  cast_bf16<<<8192, 256, 0, stream>>>(hs, hs_bf, 2097152);
  cast_bf16<<<8192, 256, 0, stream>>>(ctx, ctx_bf, 2097152);
  cast_bf16<<<1024, 256, 0, stream>>>(q_w, qw_bf, 262144);
  cast_bf16<<<1024, 256, 0, stream>>>(k_w, kw_bf, 262144);
  cast_bf16<<<1024, 256, 0, stream>>>(v_w, vw_bf, 262144);

  // QKV projections
  dim3 ggrid(MM / 128, DD / 128, 3);
  gemm_proj<<<ggrid, 256, 0, stream>>>(hs_bf, ctx_bf, qw_bf, kw_bf, vw_bf,
                                       q_b, k_b, v_b, Qb, Kb, Vtb);

  // attention
  dim3 agrid(LQ / 64, HH, BB);
  attn_kernel<<<agrid, 256, 0, stream>>>(Qb, Kb, Vtb, amask, out);
}

// Round 2
// 326.075 us; speedup vs baseline: 1.7228x; 1.7228x over previous
//
#include <hip/hip_runtime.h>
#include <hip/hip_bf16.h>
#include <stdint.h>

// Problem dims (fixed)
#define BB 4
#define LQ 2048
#define LK 2048
#define DD 1024
#define HH 16
#define HD 64
#define MM (BB * LQ)  // 8192
#define KB 64
#define NT (LK / KB)  // 32

typedef __attribute__((ext_vector_type(8))) short short8;
typedef __attribute__((ext_vector_type(4))) float f32x4;

__device__ __forceinline__ unsigned short f2bf(float x) {
  uint32_t u = __float_as_uint(x);
  u += 0x7fffu + ((u >> 16) & 1u);  // round-to-nearest-even
  return (unsigned short)(u >> 16);
}

#define GLD16(g, l)                                                  \
  __builtin_amdgcn_global_load_lds(                                  \
      (const __attribute__((address_space(1))) void*)(g),            \
      (__attribute__((address_space(3))) void*)(l), 16, 0, 0)

// XOR swizzle for [rows][128B-row] LDS tiles: spread bank groups by row&7
#define SWZ(o) ((o) ^ ((((o) >> 7) & 7) << 4))

// ---------------- fp32 -> bf16 cast (vectorized) ----------------
__global__ __launch_bounds__(256) void cast_bf16(const float* __restrict__ in,
                                                 unsigned short* __restrict__ out,
                                                 int n4) {
  int i = blockIdx.x * 256 + threadIdx.x;
  if (i >= n4) return;
  float4 v = ((const float4*)in)[i];
  ushort4 o;
  o.x = f2bf(v.x); o.y = f2bf(v.y); o.z = f2bf(v.z); o.w = f2bf(v.w);
  ((ushort4*)out)[i] = o;
}

// ---------------- mask -> additive float ----------------
__global__ __launch_bounds__(256) void mask_prep(const int* __restrict__ am,
                                                 float* __restrict__ madd, int n) {
  int i = blockIdx.x * 256 + threadIdx.x;
  if (i < n) madd[i] = (am[i] > 0) ? -1e30f : 0.f;
}

// ---------------- QKV projection GEMM (m97-style 128x128 tile) ----------------
__global__ __launch_bounds__(256) void gemm_proj(
    const unsigned short* __restrict__ hs, const unsigned short* __restrict__ ctx,
    const unsigned short* __restrict__ qw, const unsigned short* __restrict__ kw,
    const unsigned short* __restrict__ vw,
    const float* __restrict__ qb, const float* __restrict__ kb,
    const float* __restrict__ vb,
    unsigned short* __restrict__ Qo, unsigned short* __restrict__ Ko,
    unsigned short* __restrict__ Vt) {
  __shared__ unsigned short sA[128 * 32];
  __shared__ unsigned short sB[128 * 32];

  const int z = blockIdx.z;
  const unsigned short* A = (z == 0) ? hs : ctx;
  const unsigned short* W = (z == 0) ? qw : (z == 1 ? kw : vw);
  const float* bias = (z == 0) ? qb : (z == 1 ? kb : vb);
  unsigned short* out = (z == 0) ? Qo : (z == 1 ? Ko : Vt);

  const int m0 = blockIdx.x * 128;
  const int n0 = blockIdx.y * 128;
  const int t = threadIdx.x;
  const int lane = t & 63;
  const int w = t >> 6;
  const int wrow = w >> 1, wcol = w & 1;
  const int l15 = lane & 15, lg = lane >> 4;

  f32x4 acc[4][4];
#pragma unroll
  for (int i = 0; i < 4; i++)
#pragma unroll
    for (int j = 0; j < 4; j++) acc[i][j] = (f32x4){0.f, 0.f, 0.f, 0.f};

  const int c0 = t, c1 = t + 256;
  const int r0 = c0 >> 2, cc0 = (c0 & 3) * 8;
  const int r1 = c1 >> 2, cc1 = (c1 & 3) * 8;

  for (int k0 = 0; k0 < 1024; k0 += 32) {
    GLD16(A + (size_t)(m0 + r0) * 1024 + k0 + cc0, sA + (c0 & ~63) * 8);
    GLD16(W + (size_t)(n0 + r0) * 1024 + k0 + cc0, sB + (c0 & ~63) * 8);
    GLD16(A + (size_t)(m0 + r1) * 1024 + k0 + cc1, sA + (c1 & ~63) * 8);
    GLD16(W + (size_t)(n0 + r1) * 1024 + k0 + cc1, sB + (c1 & ~63) * 8);
    __syncthreads();

    short8 af[4], bf[4];
#pragma unroll
    for (int i = 0; i < 4; i++) {
      af[i] = *(const short8*)(sA + (wrow * 64 + i * 16 + l15) * 32 + lg * 8);
      bf[i] = *(const short8*)(sB + (wcol * 64 + i * 16 + l15) * 32 + lg * 8);
    }
#pragma unroll
    for (int i = 0; i < 4; i++)
#pragma unroll
      for (int j = 0; j < 4; j++)
        acc[i][j] = __builtin_amdgcn_mfma_f32_16x16x32_bf16(af[i], bf[j], acc[i][j], 0, 0, 0);
    __syncthreads();
  }

#pragma unroll
  for (int i = 0; i < 4; i++) {
    const int rowb = m0 + wrow * 64 + i * 16 + lg * 4;
#pragma unroll
    for (int j = 0; j < 4; j++) {
      const int col = n0 + wcol * 64 + j * 16 + l15;
      const float bv = bias[col];
      const int hh = col >> 6, hd = col & 63;
#pragma unroll
      for (int r = 0; r < 4; r++) {
        const int m = rowb + r;
        const int bidx = m >> 11, l = m & 2047;
        const float v = acc[i][j][r] + bv;
        size_t o;
        if (z < 2)
          o = (((size_t)(bidx * HH + hh) * 2048 + l) * HD + hd);
        else
          o = (((size_t)(bidx * HH + hh) * HD + hd) * 2048 + l);
        out[o] = f2bf(v);
      }
    }
  }
}

// ---------------- flash attention ----------------
// grid: (LQ/128, H, B), 256 threads = 4 waves; wave handles 32 q-rows (2 frags).
// K,V staged in LDS (double-buffered, swizzled); KVBLK=64.
__global__ __launch_bounds__(256) void attn_kernel(
    const unsigned short* __restrict__ Q, const unsigned short* __restrict__ K,
    const unsigned short* __restrict__ Vt, const float* __restrict__ maddf,
    float* __restrict__ out) {
  __shared__ unsigned short sK[2][4096];   // [64 k][64 d] bf16, swizzled, 8KB each
  __shared__ unsigned short sV[2][4096];   // [64 d][64 k] bf16, swizzled, 8KB each
  __shared__ unsigned short pbuf[4][1024]; // per-wave [16 q][64 k], swizzled, 2KB each

  const int b = blockIdx.z, h = blockIdx.y;
  const int t = threadIdx.x, lane = t & 63, w = t >> 6;
  const int q0 = blockIdx.x * 128 + w * 32;
  const int bh = b * HH + h;
  const int l15 = lane & 15, lg = lane >> 4;
  const int wb = t & ~63;

  const char* Kp = (const char*)(K + (size_t)bh * LK * HD);
  const char* Vp = (const char*)(Vt + (size_t)bh * HD * LK);
  const unsigned short* Qp = Q + (size_t)bh * LQ * HD;
  const float* mrow = maddf + b * LK;

  // Q fragments (A-layout), held in registers for the whole kernel
  short8 qf[2][2];
#pragma unroll
  for (int i = 0; i < 2; i++)
#pragma unroll
    for (int h2 = 0; h2 < 2; h2++)
      qf[i][h2] = *(const short8*)(Qp + (size_t)(q0 + i * 16 + l15) * HD + h2 * 32 + lg * 8);

  f32x4 acc[2][4];
  float mrun[2][4], se[2][4];
#pragma unroll
  for (int i = 0; i < 2; i++)
#pragma unroll
    for (int d = 0; d < 4; d++) acc[i][d] = (f32x4){0.f, 0.f, 0.f, 0.f};
#pragma unroll
  for (int i = 0; i < 2; i++)
#pragma unroll
    for (int r = 0; r < 4; r++) { mrun[i][r] = -1e30f; se[i][r] = 0.f; }

  auto STAGE = [&](int bufi, int k0) {
#pragma unroll
    for (int j = 0; j < 2; j++) {
      const int o = (j * 256 + t) * 16;   // linear LDS byte offset
      const int g = SWZ(o);               // pre-swizzled global source
      GLD16(Kp + (size_t)k0 * 128 + g, (char*)sK[bufi] + (j * 256 + wb) * 16);
      GLD16(Vp + (size_t)(g >> 7) * 4096 + (size_t)k0 * 2 + (g & 127),
            (char*)sV[bufi] + (j * 256 + wb) * 16);
    }
  };

  STAGE(0, 0);
  __syncthreads();

  for (int t0 = 0; t0 < NT; ++t0) {
    const int cur = t0 & 1;
    if (t0 + 1 < NT) STAGE(cur ^ 1, (t0 + 1) * KB);

    const char* sKc = (const char*)sK[cur];
    const char* sVc = (const char*)sV[cur];
    const int sw = (l15 & 7) << 4;

    // mask additive values (precomputed floats, L2-hot)
    float madd[4];
#pragma unroll
    for (int kt = 0; kt < 4; kt++) madd[kt] = mrow[t0 * KB + kt * 16 + l15];

    // --- QK^T: S[32q x 64k] as 2x4 C-frags ---
    f32x4 st[2][4];
#pragma unroll
    for (int kt = 0; kt < 4; kt++) {
      const int rowoff = (kt * 16 + l15) * 128;
      const short8 kf0 = *(const short8*)(sKc + rowoff + ((lg * 16) ^ sw));
      const short8 kf1 = *(const short8*)(sKc + rowoff + ((64 + lg * 16) ^ sw));
#pragma unroll
      for (int i = 0; i < 2; i++) {
        f32x4 tmp = __builtin_amdgcn_mfma_f32_16x16x32_bf16(qf[i][0], kf0,
                                                            (f32x4){0.f, 0.f, 0.f, 0.f}, 0, 0, 0);
        st[i][kt] = __builtin_amdgcn_mfma_f32_16x16x32_bf16(qf[i][1], kf1, tmp, 0, 0, 0);
      }
    }

    // --- per-qfrag softmax + PV ---
#pragma unroll
    for (int i = 0; i < 2; i++) {
      float p[4][4];
#pragma unroll
      for (int kt = 0; kt < 4; kt++)
#pragma unroll
        for (int r = 0; r < 4; r++) p[kt][r] = st[i][kt][r] * 0.125f + madd[kt];

      float lm[4];
#pragma unroll
      for (int r = 0; r < 4; r++)
        lm[r] = fmaxf(fmaxf(p[0][r], p[1][r]), fmaxf(p[2][r], p[3][r]));
#pragma unroll
      for (int md2 = 1; md2 <= 8; md2 <<= 1)
#pragma unroll
        for (int r = 0; r < 4; r++) lm[r] = fmaxf(lm[r], __shfl_xor(lm[r], md2));

      float fac[4];
#pragma unroll
      for (int r = 0; r < 4; r++) {
        const float nm = fmaxf(mrun[i][r], lm[r]);
        fac[r] = __expf(mrun[i][r] - nm);
        mrun[i][r] = nm;
      }
#pragma unroll
      for (int kt = 0; kt < 4; kt++)
#pragma unroll
        for (int r = 0; r < 4; r++) p[kt][r] = __expf(p[kt][r] - mrun[i][r]);

      float ls[4];
#pragma unroll
      for (int r = 0; r < 4; r++) ls[r] = (p[0][r] + p[1][r]) + (p[2][r] + p[3][r]);
#pragma unroll
      for (int md2 = 1; md2 <= 8; md2 <<= 1)
#pragma unroll
        for (int r = 0; r < 4; r++) ls[r] += __shfl_xor(ls[r], md2);
#pragma unroll
      for (int r = 0; r < 4; r++) se[i][r] = se[i][r] * fac[r] + ls[r];

      // rescale O accumulator
#pragma unroll
      for (int d = 0; d < 4; d++)
#pragma unroll
        for (int r = 0; r < 4; r++) acc[i][d][r] *= fac[r];

      // repack P (C-frag) -> LDS (swizzled [16][64]) -> A-frags; per-wave, no barrier
      char* pbw = (char*)pbuf[w];
#pragma unroll
      for (int kt = 0; kt < 4; kt++)
#pragma unroll
        for (int r = 0; r < 4; r++) {
          const int row = lg * 4 + r;
          const int off = row * 128 + ((((kt * 16 + l15) * 2)) ^ ((row & 7) << 4));
          *(unsigned short*)(pbw + off) = f2bf(p[kt][r]);
        }

      short8 pf[2];
#pragma unroll
      for (int ks = 0; ks < 2; ks++)
        pf[ks] = *(const short8*)(pbw + l15 * 128 + ((ks * 64 + lg * 16) ^ sw));

      // PV: acc += P[16x64] * V[64x64]
#pragma unroll
      for (int d = 0; d < 4; d++) {
        const int vrow = (d * 16 + l15) * 128;
#pragma unroll
        for (int ks = 0; ks < 2; ks++) {
          const short8 vf = *(const short8*)(sVc + vrow + ((ks * 64 + lg * 16) ^ sw));
          acc[i][d] = __builtin_amdgcn_mfma_f32_16x16x32_bf16(pf[ks], vf, acc[i][d], 0, 0, 0);
        }
      }
    }
    __syncthreads();  // drains stage vmcnt + all waves done with buf[cur]
  }

  // epilogue: out[b, q, h*64 + d] fp32
#pragma unroll
  for (int i = 0; i < 2; i++)
#pragma unroll
    for (int r = 0; r < 4; r++) {
      const float inv = 1.f / se[i][r];
      const int q = q0 + i * 16 + lg * 4 + r;
      float* orow = out + ((size_t)b * LQ + q) * DD + h * HD;
#pragma unroll
      for (int d = 0; d < 4; d++) orow[d * 16 + l15] = acc[i][d][r] * inv;
    }
}

extern "C" void kernel_launch(void* const* d_in, const int* in_sizes, int n_in,
                              void* d_out, int out_size, void* d_ws, size_t ws_size,
                              hipStream_t stream) {
  const float* hs = (const float*)d_in[0];
  const float* ctx = (const float*)d_in[1];
  const int* amask = (const int*)d_in[2];
  const float* q_w = (const float*)d_in[3];
  const float* q_b = (const float*)d_in[4];
  const float* k_w = (const float*)d_in[5];
  const float* k_b = (const float*)d_in[6];
  const float* v_w = (const float*)d_in[7];
  const float* v_b = (const float*)d_in[8];
  float* out = (float*)d_out;

  // workspace carve-up (ushort elements)
  unsigned short* ws = (unsigned short*)d_ws;
  unsigned short* hs_bf = ws;                     // 8192*1024
  unsigned short* ctx_bf = hs_bf + 8388608;       // 8192*1024
  unsigned short* qw_bf = ctx_bf + 8388608;       // 1024*1024
  unsigned short* kw_bf = qw_bf + 1048576;
  unsigned short* vw_bf = kw_bf + 1048576;
  unsigned short* Qb = vw_bf + 1048576;           // [B,H,LQ,HD]
  unsigned short* Kb = Qb + 8388608;              // [B,H,LK,HD]
  unsigned short* Vtb = Kb + 8388608;             // [B,H,HD,LK]
  float* maddf = (float*)(Vtb + 8388608);         // [B,LK]

  // casts + mask prep
  cast_bf16<<<8192, 256, 0, stream>>>(hs, hs_bf, 2097152);
  cast_bf16<<<8192, 256, 0, stream>>>(ctx, ctx_bf, 2097152);
  cast_bf16<<<1024, 256, 0, stream>>>(q_w, qw_bf, 262144);
  cast_bf16<<<1024, 256, 0, stream>>>(k_w, kw_bf, 262144);
  cast_bf16<<<1024, 256, 0, stream>>>(v_w, vw_bf, 262144);
  mask_prep<<<32, 256, 0, stream>>>(amask, maddf, BB * LK);

  // QKV projections
  dim3 ggrid(MM / 128, DD / 128, 3);
  gemm_proj<<<ggrid, 256, 0, stream>>>(hs_bf, ctx_bf, qw_bf, kw_bf, vw_bf,
                                       q_b, k_b, v_b, Qb, Kb, Vtb);

  // attention
  dim3 agrid(LQ / 128, HH, BB);
  attn_kernel<<<agrid, 256, 0, stream>>>(Qb, Kb, Vtb, maddf, out);
}

// Round 3
// 215.784 us; speedup vs baseline: 2.6034x; 1.5111x over previous
//
#include <hip/hip_runtime.h>
#include <hip/hip_bf16.h>
#include <stdint.h>

// Problem dims (fixed)
#define BB 4
#define LQ 2048
#define LK 2048
#define DD 1024
#define HH 16
#define HD 64
#define MM (BB * LQ)  // 8192
#define KB 64
#define NT (LK / KB)  // 32

typedef __attribute__((ext_vector_type(8))) short short8;
typedef __attribute__((ext_vector_type(4))) float f32x4;

__device__ __forceinline__ unsigned short f2bf(float x) {
  uint32_t u = __float_as_uint(x);
  u += 0x7fffu + ((u >> 16) & 1u);  // round-to-nearest-even
  return (unsigned short)(u >> 16);
}

#define GLD16(g, l)                                                  \
  __builtin_amdgcn_global_load_lds(                                  \
      (const __attribute__((address_space(1))) void*)(g),            \
      (__attribute__((address_space(3))) void*)(l), 16, 0, 0)

// XOR swizzle for [rows][128B-row] LDS tiles: spread bank groups by row&7
#define SWZ(o) ((o) ^ ((((o) >> 7) & 7) << 4))

// exp-domain constants: p = exp(s*0.125 - 8 + mask) == exp2(s*C1 + madd2)
#define C1 0.18033688f            // 0.125 * log2(e)
#define C2 (-11.5415603f)         // -8 * log2(e)

// ---------------- fp32 -> bf16 cast (vectorized) ----------------
__global__ __launch_bounds__(256) void cast_bf16(const float* __restrict__ in,
                                                 unsigned short* __restrict__ out,
                                                 int n4) {
  int i = blockIdx.x * 256 + threadIdx.x;
  if (i >= n4) return;
  float4 v = ((const float4*)in)[i];
  ushort4 o;
  o.x = f2bf(v.x); o.y = f2bf(v.y); o.z = f2bf(v.z); o.w = f2bf(v.w);
  ((ushort4*)out)[i] = o;
}

// ---------------- mask -> additive exp2-domain float ----------------
__global__ __launch_bounds__(256) void mask_prep(const int* __restrict__ am,
                                                 float* __restrict__ madd, int n) {
  int i = blockIdx.x * 256 + threadIdx.x;
  if (i < n) madd[i] = (am[i] > 0) ? -1e30f : C2;
}

// ---------------- QKV projection GEMM (m97-style 128x128 tile) ----------------
__global__ __launch_bounds__(256) void gemm_proj(
    const unsigned short* __restrict__ hs, const unsigned short* __restrict__ ctx,
    const unsigned short* __restrict__ qw, const unsigned short* __restrict__ kw,
    const unsigned short* __restrict__ vw,
    const float* __restrict__ qb, const float* __restrict__ kb,
    const float* __restrict__ vb,
    unsigned short* __restrict__ Qo, unsigned short* __restrict__ Ko,
    unsigned short* __restrict__ Vt) {
  __shared__ unsigned short sA[128 * 32];
  __shared__ unsigned short sB[128 * 32];

  const int z = blockIdx.z;
  const unsigned short* A = (z == 0) ? hs : ctx;
  const unsigned short* W = (z == 0) ? qw : (z == 1 ? kw : vw);
  const float* bias = (z == 0) ? qb : (z == 1 ? kb : vb);
  unsigned short* out = (z == 0) ? Qo : (z == 1 ? Ko : Vt);

  const int m0 = blockIdx.x * 128;
  const int n0 = blockIdx.y * 128;
  const int t = threadIdx.x;
  const int lane = t & 63;
  const int w = t >> 6;
  const int wrow = w >> 1, wcol = w & 1;
  const int l15 = lane & 15, lg = lane >> 4;

  f32x4 acc[4][4];
#pragma unroll
  for (int i = 0; i < 4; i++)
#pragma unroll
    for (int j = 0; j < 4; j++) acc[i][j] = (f32x4){0.f, 0.f, 0.f, 0.f};

  const int c0 = t, c1 = t + 256;
  const int r0 = c0 >> 2, cc0 = (c0 & 3) * 8;
  const int r1 = c1 >> 2, cc1 = (c1 & 3) * 8;

  for (int k0 = 0; k0 < 1024; k0 += 32) {
    GLD16(A + (size_t)(m0 + r0) * 1024 + k0 + cc0, sA + (c0 & ~63) * 8);
    GLD16(W + (size_t)(n0 + r0) * 1024 + k0 + cc0, sB + (c0 & ~63) * 8);
    GLD16(A + (size_t)(m0 + r1) * 1024 + k0 + cc1, sA + (c1 & ~63) * 8);
    GLD16(W + (size_t)(n0 + r1) * 1024 + k0 + cc1, sB + (c1 & ~63) * 8);
    __syncthreads();

    short8 af[4], bf[4];
#pragma unroll
    for (int i = 0; i < 4; i++) {
      af[i] = *(const short8*)(sA + (wrow * 64 + i * 16 + l15) * 32 + lg * 8);
      bf[i] = *(const short8*)(sB + (wcol * 64 + i * 16 + l15) * 32 + lg * 8);
    }
#pragma unroll
    for (int i = 0; i < 4; i++)
#pragma unroll
      for (int j = 0; j < 4; j++)
        acc[i][j] = __builtin_amdgcn_mfma_f32_16x16x32_bf16(af[i], bf[j], acc[i][j], 0, 0, 0);
    __syncthreads();
  }

#pragma unroll
  for (int i = 0; i < 4; i++) {
    const int rowb = m0 + wrow * 64 + i * 16 + lg * 4;
#pragma unroll
    for (int j = 0; j < 4; j++) {
      const int col = n0 + wcol * 64 + j * 16 + l15;
      const float bv = bias[col];
      const int hh = col >> 6, hd = col & 63;
#pragma unroll
      for (int r = 0; r < 4; r++) {
        const int m = rowb + r;
        const int bidx = m >> 11, l = m & 2047;
        const float v = acc[i][j][r] + bv;
        size_t o;
        if (z < 2)
          o = (((size_t)(bidx * HH + hh) * 2048 + l) * HD + hd);
        else
          o = (((size_t)(bidx * HH + hh) * HD + hd) * 2048 + l);
        out[o] = f2bf(v);
      }
    }
  }
}

// ---------------- flash attention (static-max, streaming softmax) ----------------
// grid: (LQ/256, H, B), 256 threads = 4 waves; wave handles 64 q-rows (4 frags).
// K,V staged in LDS (double-buffered, swizzled); KVBLK=64. se via ones-MFMA.
__global__ __launch_bounds__(256, 2) void attn_kernel(
    const unsigned short* __restrict__ Q, const unsigned short* __restrict__ K,
    const unsigned short* __restrict__ Vt, const float* __restrict__ maddf,
    float* __restrict__ out) {
  __shared__ unsigned short sK[2][4096];   // [64 k][64 d] bf16, swizzled, 8KB each
  __shared__ unsigned short sV[2][4096];   // [64 d][64 k] bf16, swizzled, 8KB each
  __shared__ unsigned short pbuf[4][4096]; // per-wave [64 q][64 k], swizzled, 8KB each

  const int b = blockIdx.z, h = blockIdx.y;
  const int t = threadIdx.x, lane = t & 63, w = t >> 6;
  const int q0 = blockIdx.x * 256 + w * 64;
  const int bh = b * HH + h;
  const int l15 = lane & 15, lg = lane >> 4;
  const int wb = t & ~63;

  const char* Kp = (const char*)(K + (size_t)bh * LK * HD);
  const char* Vp = (const char*)(Vt + (size_t)bh * HD * LK);
  const unsigned short* Qp = Q + (size_t)bh * LQ * HD;
  const float* mrow = maddf + b * LK;

  // Q fragments (A-layout), in registers for the whole kernel
  short8 qf[4][2];
#pragma unroll
  for (int i = 0; i < 4; i++)
#pragma unroll
    for (int h2 = 0; h2 < 2; h2++)
      qf[i][h2] = *(const short8*)(Qp + (size_t)(q0 + i * 16 + l15) * HD + h2 * 32 + lg * 8);

  f32x4 acc[4][4];   // [qfrag][dfrag]
  f32x4 acc_se[4];   // row-sum accumulator (all 16 cols identical)
#pragma unroll
  for (int i = 0; i < 4; i++) {
    acc_se[i] = (f32x4){0.f, 0.f, 0.f, 0.f};
#pragma unroll
    for (int d = 0; d < 4; d++) acc[i][d] = (f32x4){0.f, 0.f, 0.f, 0.f};
  }

  const short8 ones = (short8){(short)0x3F80, (short)0x3F80, (short)0x3F80, (short)0x3F80,
                               (short)0x3F80, (short)0x3F80, (short)0x3F80, (short)0x3F80};

  auto STAGE = [&](int bufi, int k0) {
#pragma unroll
    for (int j = 0; j < 2; j++) {
      const int o = (j * 256 + t) * 16;   // linear LDS byte offset
      const int g = SWZ(o);               // pre-swizzled global source
      GLD16(Kp + (size_t)k0 * 128 + g, (char*)sK[bufi] + (j * 256 + wb) * 16);
      GLD16(Vp + (size_t)(g >> 7) * 4096 + (size_t)k0 * 2 + (g & 127),
            (char*)sV[bufi] + (j * 256 + wb) * 16);
    }
  };

  STAGE(0, 0);
  __syncthreads();

  char* pbw = (char*)pbuf[w];
  const int sw = (l15 & 7) << 4;

  for (int t0 = 0; t0 < NT; ++t0) {
    const int cur = t0 & 1;
    if (t0 + 1 < NT) STAGE(cur ^ 1, (t0 + 1) * KB);

    const char* sKc = (const char*)sK[cur];
    const char* sVc = (const char*)sV[cur];

    // --- QK^T + streaming exp2 + P-store (no row coupling at all) ---
#pragma unroll
    for (int kt = 0; kt < 4; kt++) {
      const int rowoff = (kt * 16 + l15) * 128;
      const short8 kf0 = *(const short8*)(sKc + rowoff + ((lg * 16) ^ sw));
      const short8 kf1 = *(const short8*)(sKc + rowoff + ((64 + lg * 16) ^ sw));
      const float madd = mrow[t0 * KB + kt * 16 + l15];
#pragma unroll
      for (int i = 0; i < 4; i++) {
        f32x4 st = __builtin_amdgcn_mfma_f32_16x16x32_bf16(qf[i][0], kf0,
                                                           (f32x4){0.f, 0.f, 0.f, 0.f}, 0, 0, 0);
        st = __builtin_amdgcn_mfma_f32_16x16x32_bf16(qf[i][1], kf1, st, 0, 0, 0);
#pragma unroll
        for (int r = 0; r < 4; r++) {
          const float p = __builtin_amdgcn_exp2f(st[r] * C1 + madd);
          const int row = i * 16 + lg * 4 + r;
          const int off = row * 128 + ((kt * 32 + l15 * 2) ^ (((lg * 4 + r) & 7) << 4));
          *(unsigned short*)(pbw + off) = f2bf(p);
        }
      }
    }

    // --- load P as A-frags ---
    short8 pf[4][2];
#pragma unroll
    for (int i = 0; i < 4; i++)
#pragma unroll
      for (int ks = 0; ks < 2; ks++)
        pf[i][ks] = *(const short8*)(pbw + (i * 16 + l15) * 128 + ((ks * 64 + lg * 16) ^ sw));

    // --- se += P · 1  (row sums via MFMA, no shuffles) ---
#pragma unroll
    for (int i = 0; i < 4; i++) {
      acc_se[i] = __builtin_amdgcn_mfma_f32_16x16x32_bf16(pf[i][0], ones, acc_se[i], 0, 0, 0);
      acc_se[i] = __builtin_amdgcn_mfma_f32_16x16x32_bf16(pf[i][1], ones, acc_se[i], 0, 0, 0);
    }

    // --- PV: acc += P[64x64] * V[64x64], vf hoisted across qfrags ---
#pragma unroll
    for (int d = 0; d < 4; d++) {
      const int vrow = (d * 16 + l15) * 128;
#pragma unroll
      for (int ks = 0; ks < 2; ks++) {
        const short8 vf = *(const short8*)(sVc + vrow + ((ks * 64 + lg * 16) ^ sw));
#pragma unroll
        for (int i = 0; i < 4; i++)
          acc[i][d] = __builtin_amdgcn_mfma_f32_16x16x32_bf16(pf[i][ks], vf, acc[i][d], 0, 0, 0);
      }
    }
    __syncthreads();  // drains stage vmcnt + all waves done with buf[cur]
  }

  // epilogue: out[b, q, h*64 + d] fp32
#pragma unroll
  for (int i = 0; i < 4; i++)
#pragma unroll
    for (int r = 0; r < 4; r++) {
      const float inv = 1.f / acc_se[i][r];
      const int q = q0 + i * 16 + lg * 4 + r;
      float* orow = out + ((size_t)b * LQ + q) * DD + h * HD;
#pragma unroll
      for (int d = 0; d < 4; d++) orow[d * 16 + l15] = acc[i][d][r] * inv;
    }
}

extern "C" void kernel_launch(void* const* d_in, const int* in_sizes, int n_in,
                              void* d_out, int out_size, void* d_ws, size_t ws_size,
                              hipStream_t stream) {
  const float* hs = (const float*)d_in[0];
  const float* ctx = (const float*)d_in[1];
  const int* amask = (const int*)d_in[2];
  const float* q_w = (const float*)d_in[3];
  const float* q_b = (const float*)d_in[4];
  const float* k_w = (const float*)d_in[5];
  const float* k_b = (const float*)d_in[6];
  const float* v_w = (const float*)d_in[7];
  const float* v_b = (const float*)d_in[8];
  float* out = (float*)d_out;

  // workspace carve-up (ushort elements)
  unsigned short* ws = (unsigned short*)d_ws;
  unsigned short* hs_bf = ws;                     // 8192*1024
  unsigned short* ctx_bf = hs_bf + 8388608;       // 8192*1024
  unsigned short* qw_bf = ctx_bf + 8388608;       // 1024*1024
  unsigned short* kw_bf = qw_bf + 1048576;
  unsigned short* vw_bf = kw_bf + 1048576;
  unsigned short* Qb = vw_bf + 1048576;           // [B,H,LQ,HD]
  unsigned short* Kb = Qb + 8388608;              // [B,H,LK,HD]
  unsigned short* Vtb = Kb + 8388608;             // [B,H,HD,LK]
  float* maddf = (float*)(Vtb + 8388608);         // [B,LK]

  // casts + mask prep
  cast_bf16<<<8192, 256, 0, stream>>>(hs, hs_bf, 2097152);
  cast_bf16<<<8192, 256, 0, stream>>>(ctx, ctx_bf, 2097152);
  cast_bf16<<<1024, 256, 0, stream>>>(q_w, qw_bf, 262144);
  cast_bf16<<<1024, 256, 0, stream>>>(k_w, kw_bf, 262144);
  cast_bf16<<<1024, 256, 0, stream>>>(v_w, vw_bf, 262144);
  mask_prep<<<32, 256, 0, stream>>>(amask, maddf, BB * LK);

  // QKV projections
  dim3 ggrid(MM / 128, DD / 128, 3);
  gemm_proj<<<ggrid, 256, 0, stream>>>(hs_bf, ctx_bf, qw_bf, kw_bf, vw_bf,
                                       q_b, k_b, v_b, Qb, Kb, Vtb);

  // attention
  dim3 agrid(LQ / 256, HH, BB);
  attn_kernel<<<agrid, 256, 0, stream>>>(Qb, Kb, Vtb, maddf, out);
}